// Round 4
// baseline (322.247 us; speedup 1.0000x reference)
//
#include <hip/hip_runtime.h>

// Problem constants
#define N_NODES 25000
#define N_EDGES 200000
// MUL=16, NUM_RADIAL=8, HIDDEN=64, WNUMEL=1024
// PATH_ALPHA=1/sqrt(32), INV_SQRT3=1/sqrt(3), scales folded into B-fragments.

constexpr int ET = 32;        // edges per tile
constexpr int NTILES = 6250;  // 200000/32
constexpr int GRID = 512;     // persistent grid: exactly 2 blocks/CU resident
constexpr int PL = ET * 17;   // xch plane stride in floats (544)
constexpr int CFS = 152;      // cf16 per-edge stride in halfs ([e][plane*24+u], padded)

typedef __attribute__((ext_vector_type(8))) _Float16 half8;  // 8 f16 (4 VGPR)
typedef __attribute__((ext_vector_type(4))) _Float16 half4;  // 4 f16 (8B)
typedef __attribute__((ext_vector_type(4))) float float4v;   // 4 fp32

__device__ __forceinline__ half8 h8s(half8 a, _Float16 c) { return a * c; }  // v_pk_mul_f16 x4

// ---------------- fused kernel: self-connection + edge messages, atomic into zeroed out ----------------
// 512 threads, 8 waves. Wave w: prog = w>>1, uh = w&1 (u in [uh*8, uh*8+8)).
//   C[e][v] = sum_u coef[e][u] * sum_c h[e][c]*W2[c][u*16+v]*scale
// Coef planes: 0: xj0*sh0 | 1: b1 | 2: xj0 | 3+k: xj1[.,k]*sh0
// Per tile: [phase2: cf16/h16 from PREFETCHED regs] B1 [issue prefetch; phase3: MFMA+xch]
//           B2 [combine: atomics] -> loop.  Prefetch drains at B2 (hidden under MFMA).
__global__ __launch_bounds__(512, 4) void fused_kernel(
    const float* __restrict__ x, const float* __restrict__ edge_attr,
    const float* __restrict__ edge_length, const int* __restrict__ edge_src,
    const int* __restrict__ edge_dst, const float* __restrict__ W1,
    const float* __restrict__ W2, const float* __restrict__ L0,
    const float* __restrict__ L1, float* __restrict__ out) {

    const int t = threadIdx.x;
    const int w = t >> 6;             // wave id 0..7
    const int prog = w >> 1;          // which 16x16-block family of w2
    const int uh = w & 1;             // u-half
    const int qm = t & 15;            // MFMA m/n index
    const int quad = (t >> 4) & 3;    // lane quad within wave
    const int eL = t & 31;            // phase2/prefetch: edge within tile
    const int uL = t >> 5;            // phase2/prefetch: u within edge (0..15)

    __shared__ __attribute__((aligned(16))) _Float16 lds_h16[ET * 72];   // h f16, stride 72
    __shared__ __attribute__((aligned(16))) _Float16 lds_cf16[ET * CFS]; // cf f16 [e][pl*24+u]
    __shared__ __attribute__((aligned(16))) float lds_xch[12 * PL];      // term exchange
    __shared__ __attribute__((aligned(16))) float lds_w1t[64 * 8];       // W1^T [c][r]
    __shared__ __attribute__((aligned(16))) float l0[256], l1[256];      // L0, L1
    __shared__ float lds_shd[2][ET * 3];   // dbuf sh1 components for combine
    __shared__ int   lds_dstb[2][ET];      // dbuf dst for combine

    // ---- persistent B fragments: W2 block `prog`, u-half `uh`, pre-scaled f16 ----
    half8 bfr[8][2];
    {
        float scale = 0.0220970869f;                  // (1/sqrt(64)) * (1/sqrt(32))
        if (prog == 1) scale *= 0.5773502692f;        // INV_SQRT3 folded
        const int kr = quad * 8;
        #pragma unroll
        for (int up = 0; up < 8; ++up) {
            const int col = prog * 256 + (uh * 8 + up) * 16 + qm;
            #pragma unroll
            for (int kf = 0; kf < 2; ++kf) {
                half8 f;
                #pragma unroll
                for (int j = 0; j < 8; ++j) {
                    const int k = kf * 32 + kr + j;
                    f[j] = (_Float16)(W2[k * 1024 + col] * scale);
                }
                bfr[up][kf] = f;
            }
        }
    }
    // W1 -> LDS transposed [c][r]; L0/L1 -> LDS
    lds_w1t[(t & 63) * 8 + (t >> 6)] = W1[t];
    if (t < 256) l0[t] = L0[t];
    else         l1[t - 256] = L1[t - 256];

    // ---- prologue: gather tile T into regs; src for T+GRID ----
    int T = blockIdx.x;
    float g_xj0, g_x0, g_x1, g_x2, g_len;
    float4v g_ea;
    int g_dst, s_next;
    {
        const int eg = T * ET + eL;                  // T < GRID <= NTILES -> in bounds
        const int src = edge_src[eg];
        const float* xr = x + src * 64;
        g_xj0 = xr[uL];
        g_x0 = xr[16 + 3 * uL];
        g_x1 = xr[17 + 3 * uL];
        g_x2 = xr[18 + 3 * uL];
        g_ea  = *(const float4v*)(edge_attr + 4 * eg);
        g_len = edge_length[eg];
        g_dst = edge_dst[eg];
        const int egn = min((T + GRID) * ET + eL, N_EDGES - 1);
        s_next = edge_src[egn];
    }

    __syncthreads();   // w1t/l0/l1 visible

    // ---- self-connection: wave-shuffle matvec, atomicAdd into zeroed out ----
    {
        const int lane = t & 63;
        const bool is0 = lane < 16;
        const int q = lane - 16;
        const int v = is0 ? lane : q / 3;
        const int k = is0 ? 0 : q - 3 * v;
        const float* mat = is0 ? l0 : l1;
        for (int n = blockIdx.x * 8 + w; n < N_NODES; n += GRID * 8) {
            const float xv = x[n * 64 + lane];
            float s = 0.f;
            #pragma unroll
            for (int u = 0; u < 16; ++u) {
                const int sel = is0 ? u : 16 + 3 * u + k;
                s = fmaf(__shfl(xv, sel), mat[u * 16 + v], s);
            }
            atomicAdd(out + n * 64 + lane, 0.25f * s);   // 1/sqrt(MUL)
        }
    }

    int p = 0;
    while (true) {
        // ---- phase 2: cf16 + h16 from regs (LDS writes only) ----
        {
            const float sh0 = g_ea[0], s1x = g_ea[1], s1y = g_ea[2], s1z = g_ea[3];
            _Float16* cfb = &lds_cf16[eL * CFS + uL];
            cfb[0 * 24] = (_Float16)(g_xj0 * sh0);
            cfb[1 * 24] = (_Float16)fmaf(g_x0, s1x, fmaf(g_x1, s1y, g_x2 * s1z));
            cfb[2 * 24] = (_Float16)g_xj0;
            cfb[3 * 24] = (_Float16)(g_x0 * sh0);
            cfb[4 * 24] = (_Float16)(g_x1 * sh0);
            cfb[5 * 24] = (_Float16)(g_x2 * sh0);
            if (uL == 0) {
                lds_shd[p][eL * 3 + 0] = s1x;
                lds_shd[p][eL * 3 + 1] = s1y;
                lds_shd[p][eL * 3 + 2] = s1z;
                lds_dstb[p][eL] = g_dst;
            }
            // h = silu(radial @ W1 / sqrt(8)) for (e=eL, c = uL*4 .. +3), stored f16
            const int c0 = uL * 4;
            float rad[8];
            #pragma unroll
            for (int r = 0; r < 8; ++r) {
                const float d = g_len - 0.7142857143f * (float)r;
                rad[r] = __expf(-0.5f * d * d);
            }
            half4 hv;
            #pragma unroll
            for (int i = 0; i < 4; ++i) {
                const float4v wA = *(const float4v*)(&lds_w1t[(c0 + i) * 8]);
                const float4v wB = *(const float4v*)(&lds_w1t[(c0 + i) * 8 + 4]);
                float s = rad[0] * wA[0] + rad[1] * wA[1] + rad[2] * wA[2] + rad[3] * wA[3]
                        + rad[4] * wB[0] + rad[5] * wB[1] + rad[6] * wB[2] + rad[7] * wB[3];
                s *= 0.3535533906f;
                hv[i] = (_Float16)(s / (1.f + __expf(-s)));
            }
            *(half4*)(&lds_h16[eL * 72 + c0]) = hv;
        }

        __syncthreads();   // B1: cf16/h16/shd visible

        // ---- issue next-tile prefetch; drains at B2, hidden under MFMA ----
        const int Tn = T + GRID;
        if (Tn < NTILES) {
            const float* xr = x + s_next * 64;
            g_xj0 = xr[uL];
            g_x0 = xr[16 + 3 * uL];
            g_x1 = xr[17 + 3 * uL];
            g_x2 = xr[18 + 3 * uL];
            const int eg = Tn * ET + eL;
            g_ea  = *(const float4v*)(edge_attr + 4 * eg);
            g_len = edge_length[eg];
            g_dst = edge_dst[eg];
            const int egn = min((Tn + GRID) * ET + eL, N_EDGES - 1);
            s_next = edge_src[egn];
        }

        // ---- phase 3: A frags + coef-scaled MFMA + xch (kf-split to save regs) ----
        if (prog < 3) {
            half8 cfv[2];
            #pragma unroll
            for (int mt = 0; mt < 2; ++mt)
                cfv[mt] = *(const half8*)(&lds_cf16[(mt * 16 + qm) * CFS + prog * 24 + uh * 8]);
            float4v acc[2];
            acc[0] = (float4v){0.f, 0.f, 0.f, 0.f};
            acc[1] = (float4v){0.f, 0.f, 0.f, 0.f};
            #pragma unroll
            for (int kf = 0; kf < 2; ++kf) {
                half8 ah[2];
                #pragma unroll
                for (int mt = 0; mt < 2; ++mt)
                    ah[mt] = *(const half8*)(&lds_h16[(mt * 16 + qm) * 72 + kf * 32 + quad * 8]);
                #pragma unroll
                for (int up = 0; up < 8; ++up)
                    #pragma unroll
                    for (int mt = 0; mt < 2; ++mt)
                        acc[mt] = __builtin_amdgcn_mfma_f32_16x16x32_f16(
                            h8s(ah[mt], cfv[mt][up]), bfr[up][kf], acc[mt], 0, 0, 0);
            }
            float* xb = &lds_xch[w * PL];
            #pragma unroll
            for (int mt = 0; mt < 2; ++mt)
                #pragma unroll
                for (int r = 0; r < 4; ++r)
                    xb[(mt * 16 + quad * 4 + r) * 17 + qm] = acc[mt][r];
        } else {
            #pragma unroll
            for (int k = 0; k < 3; ++k) {   // sequential k-planes: acc stays 8 regs
                half8 cfv[2];
                #pragma unroll
                for (int mt = 0; mt < 2; ++mt)
                    cfv[mt] = *(const half8*)(&lds_cf16[(mt * 16 + qm) * CFS + (3 + k) * 24 + uh * 8]);
                float4v acc[2];
                acc[0] = (float4v){0.f, 0.f, 0.f, 0.f};
                acc[1] = (float4v){0.f, 0.f, 0.f, 0.f};
                #pragma unroll
                for (int kf = 0; kf < 2; ++kf) {
                    half8 ah[2];
                    #pragma unroll
                    for (int mt = 0; mt < 2; ++mt)
                        ah[mt] = *(const half8*)(&lds_h16[(mt * 16 + qm) * 72 + kf * 32 + quad * 8]);
                    #pragma unroll
                    for (int up = 0; up < 8; ++up)
                        #pragma unroll
                        for (int mt = 0; mt < 2; ++mt)
                            acc[mt] = __builtin_amdgcn_mfma_f32_16x16x32_f16(
                                h8s(ah[mt], cfv[mt][up]), bfr[up][kf], acc[mt], 0, 0, 0);
                }
                float* xb = &lds_xch[(6 + uh * 3 + k) * PL];
                #pragma unroll
                for (int mt = 0; mt < 2; ++mt)
                    #pragma unroll
                    for (int r = 0; r < 4; ++r)
                        xb[(mt * 16 + quad * 4 + r) * 17 + qm] = acc[mt][r];
            }
        }

        __syncthreads();   // B2: xch visible; prefetch drained here (under MFMA)

        // ---- combine: 4 output elems per thread, ONE atomic each ----
        #pragma unroll
        for (int i = 0; i < 4; ++i) {
            const int idx = t + 512 * i;          // 2048 = 32 edges x 64 elems
            const int e = idx >> 6, j = idx & 63;
            float val;
            if (j < 16) {
                val = (lds_xch[0 * PL + e * 17 + j] + lds_xch[1 * PL + e * 17 + j])
                    + (lds_xch[2 * PL + e * 17 + j] + lds_xch[3 * PL + e * 17 + j]);
            } else {
                const int q = j - 16, v = q / 3, k = q - 3 * v;
                const float s2 = lds_xch[4 * PL + e * 17 + v] + lds_xch[5 * PL + e * 17 + v];
                const float s3 = lds_xch[(6 + k) * PL + e * 17 + v]
                               + lds_xch[(9 + k) * PL + e * 17 + v];
                val = fmaf(s2, lds_shd[p][e * 3 + k], s3);
            }
            atomicAdd(out + lds_dstb[p][e] * 64 + j, val);
        }

        T = Tn;
        if (T >= NTILES) break;
        p ^= 1;
        // next-iter phase2 writes cf16/h16 (readers finished before B2) and buffer p^1.
    }
}

extern "C" void kernel_launch(void* const* d_in, const int* in_sizes, int n_in,
                              void* d_out, int out_size, void* d_ws, size_t ws_size,
                              hipStream_t stream) {
    const float* x           = (const float*)d_in[0];
    const float* edge_attr   = (const float*)d_in[1];
    const float* edge_length = (const float*)d_in[2];
    const int*   edge_src    = (const int*)d_in[3];
    const int*   edge_dst    = (const int*)d_in[4];
    const float* W1          = (const float*)d_in[5];
    const float* W2          = (const float*)d_in[6];
    const float* L0          = (const float*)d_in[7];
    const float* L1          = (const float*)d_in[8];
    float* out = (float*)d_out;

    hipMemsetAsync(out, 0, (size_t)N_NODES * 64 * sizeof(float), stream);
    fused_kernel<<<GRID, 512, 0, stream>>>(
        x, edge_attr, edge_length, edge_src, edge_dst, W1, W2, L0, L1, out);
}

// Round 5
// 209.346 us; speedup vs baseline: 1.5393x; 1.5393x over previous
//
#include <hip/hip_runtime.h>

// Problem constants
#define N_NODES 25000
#define N_EDGES 200000
// MUL=16, NUM_RADIAL=8, HIDDEN=64, WNUMEL=1024
// PATH_ALPHA=1/sqrt(32), INV_SQRT3=1/sqrt(3), scales folded into B-fragments.

constexpr int ET = 32;        // edges per tile
constexpr int NTILES = 6250;  // 200000/32
constexpr int GRID = 512;     // persistent grid: 2 blocks/CU resident
constexpr int PL = ET * 17;   // xch plane stride in floats (544)
constexpr int CFS = 152;      // cf16 per-edge stride in halfs (16B-aligned rows)

typedef __attribute__((ext_vector_type(8))) _Float16 half8;  // 8 f16 (4 VGPR)
typedef __attribute__((ext_vector_type(4))) _Float16 half4;  // 4 f16 (8B)
typedef __attribute__((ext_vector_type(4))) float float4v;   // 4 fp32

__device__ __forceinline__ half8 h8s(half8 a, _Float16 c) { return a * c; }  // v_pk_mul_f16 x4

// Async global->LDS (no dest VGPRs; global addr is per-lane, LDS dest = base + lane*size).
__device__ __forceinline__ void gl_lds16(const void* g, void* l) {
    __builtin_amdgcn_global_load_lds((const __attribute__((address_space(1))) void*)g,
                                     (__attribute__((address_space(3))) void*)l, 16, 0, 0);
}
__device__ __forceinline__ void gl_lds4(const void* g, void* l) {
    __builtin_amdgcn_global_load_lds((const __attribute__((address_space(1))) void*)g,
                                     (__attribute__((address_space(3))) void*)l, 4, 0, 0);
}

// ---------------- fused kernel: sc + edge messages, atomics into zeroed out ----------------
// 512 threads, 8 waves. Wave w: prog = w>>1, uh = w&1.
//   C[e][v] = sum_u coef[e][u] * sum_c h[e][c]*W2[c][u*16+v]*scale
// Coef planes: 0: xj0*sh0 | 1: b1 | 2: xj0 | 3+k: xj1[.,k]*sh0
// Per tile: [phase2: cf16/h16 from LDS buffers[p]] B1 [issue async stage of T+1 into
// buffers[p^1]; phase3: MFMA+xch] B2(drains stage under MFMA) [combine: atomics] -> loop.
__global__ __launch_bounds__(512, 4) void fused_kernel(
    const float* __restrict__ x, const float* __restrict__ edge_attr,
    const float* __restrict__ edge_length, const int* __restrict__ edge_src,
    const int* __restrict__ edge_dst, const float* __restrict__ W1,
    const float* __restrict__ W2, const float* __restrict__ L0,
    const float* __restrict__ L1, float* __restrict__ out) {

    const int t = threadIdx.x;
    const int w = t >> 6;             // wave id 0..7
    const int lane = t & 63;
    const int prog = w >> 1;          // which 16x16-block family of w2
    const int uh = w & 1;             // u-half
    const int qm = t & 15;            // MFMA m/n index
    const int quad = (t >> 4) & 3;    // lane quad within wave
    const int eL = t >> 4;            // phase2: edge within tile (0..31)
    const int uL = t & 15;            // phase2: u within edge (0..15)

    __shared__ __attribute__((aligned(16))) _Float16 lds_h16[ET * 72];   // h f16, stride 72
    __shared__ __attribute__((aligned(16))) _Float16 lds_cf16[ET * CFS]; // cf f16 [e][pl*24+u]
    __shared__ __attribute__((aligned(16))) float lds_xch[12 * PL];      // term exchange
    __shared__ __attribute__((aligned(16))) float lds_w1t[64 * 8];       // W1^T [c][r]
    __shared__ __attribute__((aligned(16))) float l0[256], l1[256];      // L0, L1
    __shared__ __attribute__((aligned(16))) float lds_xj[2][ET * 64];    // dbuf x[src], LINEAR stride 64
    __shared__ __attribute__((aligned(16))) float lds_ea[2][ET * 4];     // dbuf edge_attr
    __shared__ __attribute__((aligned(16))) float lds_len[2][ET];
    __shared__ __attribute__((aligned(16))) int   lds_dst[2][ET];
    __shared__ __attribute__((aligned(16))) int   lds_srcb[2][ET];       // srcb[p] = src(T+1)

    // ---- persistent B fragments: W2 block `prog`, u-half `uh`, pre-scaled f16 ----
    half8 bfr[8][2];
    {
        float scale = 0.0220970869f;                  // (1/sqrt(64)) * (1/sqrt(32))
        if (prog == 1) scale *= 0.5773502692f;        // INV_SQRT3 folded
        const int kr = quad * 8;
        #pragma unroll
        for (int up = 0; up < 8; ++up) {
            const int col = prog * 256 + (uh * 8 + up) * 16 + qm;
            #pragma unroll
            for (int kf = 0; kf < 2; ++kf) {
                half8 f;
                #pragma unroll
                for (int j = 0; j < 8; ++j) {
                    const int k = kf * 32 + kr + j;
                    f[j] = (_Float16)(W2[k * 1024 + col] * scale);
                }
                bfr[up][kf] = f;
            }
        }
    }
    // W1 -> LDS transposed [c][r]; L0/L1 -> LDS
    lds_w1t[(t & 63) * 8 + (t >> 6)] = W1[t];
    if (t < 256) l0[t] = L0[t];
    else         l1[t - 256] = L1[t - 256];

    // ---- prologue: async-stage tile T into buffers[0]; srcb[0] = src(T+1) ----
    int T = blockIdx.x;
    if (w == 0 && lane < ET) gl_lds4(edge_src + T * ET + lane, &lds_srcb[1][0]);
    __syncthreads();   // srcb[1]=src(T) visible; w1t/l0/l1 visible
    {
        const int e4 = (w << 2) + (lane >> 4);
        const int src = lds_srcb[1][e4];
        gl_lds16(x + src * 64 + (lane & 15) * 4, &lds_xj[0][w * 256]);
    }
    if (w == 0 && lane < ET) gl_lds16(edge_attr + 4 * (T * ET + lane), &lds_ea[0][0]);
    if (w == 1 && lane < ET) gl_lds4(edge_length + T * ET + lane, &lds_len[0][0]);
    if (w == 2 && lane < ET) gl_lds4(edge_dst + T * ET + lane, &lds_dst[0][0]);
    if (w == 3 && lane < ET) {
        const int Tn = (T + GRID < NTILES) ? T + GRID : T;
        gl_lds4(edge_src + Tn * ET + lane, &lds_srcb[0][0]);
    }

    // ---- self-connection under the stage latency: shuffle matvec + atomics ----
    {
        const bool is0 = lane < 16;
        const int q = lane - 16;
        const int v = is0 ? lane : q / 3;
        const int k = is0 ? 0 : q - 3 * v;
        const float* mat = is0 ? l0 : l1;
        for (int n = blockIdx.x * 8 + w; n < N_NODES; n += GRID * 8) {
            const float xv = x[n * 64 + lane];
            float s = 0.f;
            #pragma unroll
            for (int u = 0; u < 16; ++u) {
                const int sel = is0 ? u : 16 + 3 * u + k;
                s = fmaf(__shfl(xv, sel), mat[u * 16 + v], s);
            }
            atomicAdd(out + n * 64 + lane, 0.25f * s);   // 1/sqrt(MUL)
        }
    }
    __syncthreads();   // drains prologue stage (+sc atomics): buffers[0] ready

    int p = 0;
    while (true) {
        // ---- phase 2: cf16 + h16 from buffers[p] (thread = (eL, uL)) ----
        {
            const float sh0 = lds_ea[p][eL * 4 + 0];
            const float s1x = lds_ea[p][eL * 4 + 1];
            const float s1y = lds_ea[p][eL * 4 + 2];
            const float s1z = lds_ea[p][eL * 4 + 3];
            const float* xr = &lds_xj[p][eL * 64];
            const float xj0v = xr[uL];
            const float x0 = xr[16 + 3 * uL];
            const float x1 = xr[17 + 3 * uL];
            const float x2 = xr[18 + 3 * uL];
            _Float16* cfb = &lds_cf16[eL * CFS + uL];
            cfb[0 * 24] = (_Float16)(xj0v * sh0);
            cfb[1 * 24] = (_Float16)fmaf(x0, s1x, fmaf(x1, s1y, x2 * s1z));
            cfb[2 * 24] = (_Float16)xj0v;
            cfb[3 * 24] = (_Float16)(x0 * sh0);
            cfb[4 * 24] = (_Float16)(x1 * sh0);
            cfb[5 * 24] = (_Float16)(x2 * sh0);
            // h = silu(radial @ W1 / sqrt(8)) for (e=eL, c = uL*4 .. +3), stored f16
            const int c0 = uL * 4;
            const float len = lds_len[p][eL];
            float rad[8];
            #pragma unroll
            for (int r = 0; r < 8; ++r) {
                const float d = len - 0.7142857143f * (float)r;
                rad[r] = __expf(-0.5f * d * d);
            }
            half4 hv;
            #pragma unroll
            for (int i = 0; i < 4; ++i) {
                const float4v wA = *(const float4v*)(&lds_w1t[(c0 + i) * 8]);
                const float4v wB = *(const float4v*)(&lds_w1t[(c0 + i) * 8 + 4]);
                float s = rad[0] * wA[0] + rad[1] * wA[1] + rad[2] * wA[2] + rad[3] * wA[3]
                        + rad[4] * wB[0] + rad[5] * wB[1] + rad[6] * wB[2] + rad[7] * wB[3];
                s *= 0.3535533906f;
                hv[i] = (_Float16)(s / (1.f + __expf(-s)));
            }
            *(half4*)(&lds_h16[eL * 72 + c0]) = hv;
        }

        __syncthreads();   // B1: cf16/h16 visible

        // ---- issue async stage of tile T+1 into buffers[p^1] (zero registers) ----
        const int Tn = T + GRID;
        if (Tn < NTILES) {
            const int pn = p ^ 1;
            {
                const int e4 = (w << 2) + (lane >> 4);
                const int src = lds_srcb[p][e4];
                gl_lds16(x + src * 64 + (lane & 15) * 4, &lds_xj[pn][w * 256]);
            }
            if (w == 0 && lane < ET) gl_lds16(edge_attr + 4 * (Tn * ET + lane), &lds_ea[pn][0]);
            if (w == 1 && lane < ET) gl_lds4(edge_length + Tn * ET + lane, &lds_len[pn][0]);
            if (w == 2 && lane < ET) gl_lds4(edge_dst + Tn * ET + lane, &lds_dst[pn][0]);
            if (w == 3 && lane < ET) {
                const int T2 = (Tn + GRID < NTILES) ? Tn + GRID : Tn;
                gl_lds4(edge_src + T2 * ET + lane, &lds_srcb[pn][0]);
            }
        }

        // ---- phase 3: A frags + coef-scaled MFMA + xch (kf-split, low regs) ----
        if (prog < 3) {
            half8 cfv[2];
            #pragma unroll
            for (int mt = 0; mt < 2; ++mt)
                cfv[mt] = *(const half8*)(&lds_cf16[(mt * 16 + qm) * CFS + prog * 24 + uh * 8]);
            float4v acc[2];
            acc[0] = (float4v){0.f, 0.f, 0.f, 0.f};
            acc[1] = (float4v){0.f, 0.f, 0.f, 0.f};
            #pragma unroll
            for (int kf = 0; kf < 2; ++kf) {
                half8 ah[2];
                #pragma unroll
                for (int mt = 0; mt < 2; ++mt)
                    ah[mt] = *(const half8*)(&lds_h16[(mt * 16 + qm) * 72 + kf * 32 + quad * 8]);
                #pragma unroll
                for (int up = 0; up < 8; ++up)
                    #pragma unroll
                    for (int mt = 0; mt < 2; ++mt)
                        acc[mt] = __builtin_amdgcn_mfma_f32_16x16x32_f16(
                            h8s(ah[mt], cfv[mt][up]), bfr[up][kf], acc[mt], 0, 0, 0);
            }
            float* xb = &lds_xch[w * PL];
            #pragma unroll
            for (int mt = 0; mt < 2; ++mt)
                #pragma unroll
                for (int r = 0; r < 4; ++r)
                    xb[(mt * 16 + quad * 4 + r) * 17 + qm] = acc[mt][r];
        } else {
            #pragma unroll
            for (int k = 0; k < 3; ++k) {   // sequential k-planes: acc stays 8 regs
                half8 cfv[2];
                #pragma unroll
                for (int mt = 0; mt < 2; ++mt)
                    cfv[mt] = *(const half8*)(&lds_cf16[(mt * 16 + qm) * CFS + (3 + k) * 24 + uh * 8]);
                float4v acc[2];
                acc[0] = (float4v){0.f, 0.f, 0.f, 0.f};
                acc[1] = (float4v){0.f, 0.f, 0.f, 0.f};
                #pragma unroll
                for (int kf = 0; kf < 2; ++kf) {
                    half8 ah[2];
                    #pragma unroll
                    for (int mt = 0; mt < 2; ++mt)
                        ah[mt] = *(const half8*)(&lds_h16[(mt * 16 + qm) * 72 + kf * 32 + quad * 8]);
                    #pragma unroll
                    for (int up = 0; up < 8; ++up)
                        #pragma unroll
                        for (int mt = 0; mt < 2; ++mt)
                            acc[mt] = __builtin_amdgcn_mfma_f32_16x16x32_f16(
                                h8s(ah[mt], cfv[mt][up]), bfr[up][kf], acc[mt], 0, 0, 0);
                }
                float* xb = &lds_xch[(6 + uh * 3 + k) * PL];
                #pragma unroll
                for (int mt = 0; mt < 2; ++mt)
                    #pragma unroll
                    for (int r = 0; r < 4; ++r)
                        xb[(mt * 16 + quad * 4 + r) * 17 + qm] = acc[mt][r];
            }
        }

        __syncthreads();   // B2: xch visible; stage of T+1 drained (hidden under MFMA)

        // ---- combine: 4 output elems per thread, ONE atomic each ----
        #pragma unroll
        for (int i = 0; i < 4; ++i) {
            const int idx = t + 512 * i;          // 2048 = 32 edges x 64 elems
            const int e = idx >> 6, j = idx & 63;
            float val;
            if (j < 16) {
                val = (lds_xch[0 * PL + e * 17 + j] + lds_xch[1 * PL + e * 17 + j])
                    + (lds_xch[2 * PL + e * 17 + j] + lds_xch[3 * PL + e * 17 + j]);
            } else {
                const int q = j - 16, v = q / 3, k = q - 3 * v;
                const float s2 = lds_xch[4 * PL + e * 17 + v] + lds_xch[5 * PL + e * 17 + v];
                const float s3 = lds_xch[(6 + k) * PL + e * 17 + v]
                               + lds_xch[(9 + k) * PL + e * 17 + v];
                val = fmaf(s2, lds_ea[p][e * 4 + 1 + k], s3);
            }
            atomicAdd(out + lds_dst[p][e] * 64 + j, val);
        }

        if (Tn >= NTILES) break;
        T = Tn;
        p ^= 1;
        // next phase 2 reads buffers[p^1] (drained at B2); atomics overlap next phase 2,
        // drained at next B1.
    }
}

extern "C" void kernel_launch(void* const* d_in, const int* in_sizes, int n_in,
                              void* d_out, int out_size, void* d_ws, size_t ws_size,
                              hipStream_t stream) {
    const float* x           = (const float*)d_in[0];
    const float* edge_attr   = (const float*)d_in[1];
    const float* edge_length = (const float*)d_in[2];
    const int*   edge_src    = (const int*)d_in[3];
    const int*   edge_dst    = (const int*)d_in[4];
    const float* W1          = (const float*)d_in[5];
    const float* W2          = (const float*)d_in[6];
    const float* L0          = (const float*)d_in[7];
    const float* L1          = (const float*)d_in[8];
    float* out = (float*)d_out;

    hipMemsetAsync(out, 0, (size_t)N_NODES * 64 * sizeof(float), stream);
    fused_kernel<<<GRID, 512, 0, stream>>>(
        x, edge_attr, edge_length, edge_src, edge_dst, W1, W2, L0, L1, out);
}